// Round 1
// baseline (496.305 us; speedup 1.0000x reference)
//
#include <hip/hip_runtime.h>
#include <hip/hip_bf16.h>

// SimpleAttention: B=4, L=2048, D=1024, H=16, dh=64.
// Pipeline: cvt(x)->bf16 ; transpose-cvt(w_qkv,w_out)->[N][K] bf16 ;
//           QKV GEMM (writes Q*0.125,K as [B,H,L,64], V^T as [B,H,64,L]) ;
//           flash attention (causal, online softmax) -> AO [B*L][1024] bf16 ;
//           out GEMM -> f32 d_out.

typedef __attribute__((ext_vector_type(4))) float f32x4;
typedef __attribute__((ext_vector_type(8))) short bf16x8;

__device__ inline unsigned short f2bf(float f) {
  unsigned int u = __float_as_uint(f);
  u += 0x7FFFu + ((u >> 16) & 1u);   // RNE
  return (unsigned short)(u >> 16);
}

__device__ inline void gl_lds16(const void* g, void* l) {
  __builtin_amdgcn_global_load_lds(
      (const __attribute__((address_space(1))) unsigned int*)g,
      (__attribute__((address_space(3))) unsigned int*)l, 16, 0, 0);
}

// ---------------- elementwise f32 -> bf16 ----------------
__global__ __launch_bounds__(256) void cvt_bf16(const float* __restrict__ src,
                                                unsigned short* __restrict__ dst,
                                                int n4) {
  int stride = gridDim.x * blockDim.x;
  for (int i = blockIdx.x * blockDim.x + threadIdx.x; i < n4; i += stride) {
    float4 v = ((const float4*)src)[i];
    ushort4 o;
    o.x = f2bf(v.x); o.y = f2bf(v.y); o.z = f2bf(v.z); o.w = f2bf(v.w);
    ((ushort4*)dst)[i] = o;
  }
}

// ---------------- transpose + convert: src f32 [K][N] -> dst bf16 [N][K] ----
__global__ __launch_bounds__(256) void transpose_cvt(const float* __restrict__ src,
                                                     unsigned short* __restrict__ dst,
                                                     int K, int N) {
  __shared__ float tile[64][65];
  const int k0 = blockIdx.y * 64, n0 = blockIdx.x * 64;
  const int t = threadIdx.x;
  const int tr = t >> 2, tq = t & 3;
  const float* s = src + (size_t)(k0 + tr) * N + n0 + tq * 16;
#pragma unroll
  for (int i = 0; i < 4; ++i) {
    float4 v = *(const float4*)(s + i * 4);
    tile[tr][tq * 16 + i * 4 + 0] = v.x;
    tile[tr][tq * 16 + i * 4 + 1] = v.y;
    tile[tr][tq * 16 + i * 4 + 2] = v.z;
    tile[tr][tq * 16 + i * 4 + 3] = v.w;
  }
  __syncthreads();
  unsigned short* d = dst + (size_t)(n0 + tr) * K + k0 + tq * 16;
#pragma unroll
  for (int i = 0; i < 4; ++i) {
    ushort4 o;
    o.x = f2bf(tile[tq * 16 + i * 4 + 0][tr]);
    o.y = f2bf(tile[tq * 16 + i * 4 + 1][tr]);
    o.z = f2bf(tile[tq * 16 + i * 4 + 2][tr]);
    o.w = f2bf(tile[tq * 16 + i * 4 + 3][tr]);
    *(ushort4*)(d + i * 4) = o;
  }
}

// ---------------- GEMM: A [M][K] bf16  x  Bt [N][K] bf16 -------------------
// 128x128 tile, BK=64, 4 waves (each 64x64 = 4x4 16x16 frags).
// LDS linear dest + inverse-swizzled global source + swizzled ds_read (rule #21).
// EPI==0: QKV epilogue (scatter Q/K/VT).  EPI==1: f32 C write.
template <int EPI>
__global__ __launch_bounds__(256) void gemm_bt(
    const unsigned short* __restrict__ A, const unsigned short* __restrict__ Bt,
    float* __restrict__ Cf,
    unsigned short* __restrict__ Qb, unsigned short* __restrict__ Kb,
    unsigned short* __restrict__ VTb, int M, int N, int K) {
  __shared__ unsigned short lds[16384];  // bytes [0,16384)=A [128][64], [16384,32768)=B^T [128][64]
  const int tid = threadIdx.x;
  const int lane = tid & 63, wid = tid >> 6;
  const int wr = wid >> 1, wc = wid & 1;
  const int l15 = lane & 15, g = lane >> 4;
  const int bm = blockIdx.y * 128, bn = blockIdx.x * 128;

  f32x4 acc[4][4];
#pragma unroll
  for (int m = 0; m < 4; ++m)
#pragma unroll
    for (int n = 0; n < 4; ++n) acc[m][n] = (f32x4){0.f, 0.f, 0.f, 0.f};

  const int nkt = K >> 6;
  for (int kt = 0; kt < nkt; ++kt) {
    const int k0 = kt << 6;
#pragma unroll
    for (int i = 0; i < 4; ++i) {  // A tile: 1024 segs of 16B
      int seg = wid * 256 + i * 64 + lane;
      int row = seg >> 3, slot = seg & 7;
      int ls = slot ^ (row & 7);  // inverse swizzle on the SOURCE
      gl_lds16(A + (size_t)(bm + row) * K + k0 + ls * 8,
               (void*)((char*)lds + seg * 16));
    }
#pragma unroll
    for (int i = 0; i < 4; ++i) {  // B^T tile
      int seg = wid * 256 + i * 64 + lane;
      int row = seg >> 3, slot = seg & 7;
      int ls = slot ^ (row & 7);
      gl_lds16(Bt + (size_t)(bn + row) * K + k0 + ls * 8,
               (void*)((char*)lds + 16384 + seg * 16));
    }
    __syncthreads();
#pragma unroll
    for (int ks = 0; ks < 2; ++ks) {
      bf16x8 af[4], bfr[4];
#pragma unroll
      for (int m = 0; m < 4; ++m) {
        int r = wr * 64 + m * 16 + l15;
        int cb = (ks * 64 + g * 16) ^ ((r & 7) << 4);  // swizzled read
        af[m] = *(const bf16x8*)((const char*)lds + r * 128 + cb);
      }
#pragma unroll
      for (int n = 0; n < 4; ++n) {
        int r = wc * 64 + n * 16 + l15;
        int cb = (ks * 64 + g * 16) ^ ((r & 7) << 4);
        bfr[n] = *(const bf16x8*)((const char*)lds + 16384 + r * 128 + cb);
      }
#pragma unroll
      for (int m = 0; m < 4; ++m)
#pragma unroll
        for (int n = 0; n < 4; ++n)
          acc[m][n] = __builtin_amdgcn_mfma_f32_16x16x32_bf16(af[m], bfr[n],
                                                              acc[m][n], 0, 0, 0);
    }
    __syncthreads();
  }

  const int g4 = g * 4;
#pragma unroll
  for (int m = 0; m < 4; ++m) {
#pragma unroll
    for (int n = 0; n < 4; ++n) {
      const int col = bn + wc * 64 + n * 16 + l15;
      const int row0 = bm + wr * 64 + m * 16 + g4;
      if (EPI == 1) {
#pragma unroll
        for (int r = 0; r < 4; ++r)
          Cf[(size_t)(row0 + r) * N + col] = acc[m][n][r];
      } else {
        const int t3 = col >> 10, rem = col & 1023;
        const int h = rem >> 6, d = rem & 63;
        const int b = row0 >> 11, li0 = row0 & 2047;
        const size_t bh = (size_t)(b * 16 + h);
        if (t3 == 2) {  // V^T: 4 consecutive l at fixed d -> packed 8B store
          ushort4 o;
          o.x = f2bf(acc[m][n][0]); o.y = f2bf(acc[m][n][1]);
          o.z = f2bf(acc[m][n][2]); o.w = f2bf(acc[m][n][3]);
          *(ushort4*)&VTb[(bh * 64 + d) * 2048 + li0] = o;
        } else {
#pragma unroll
          for (int r = 0; r < 4; ++r) {
            float v = acc[m][n][r];
            if (t3 == 0)
              Qb[(bh * 2048 + (li0 + r)) * 64 + d] = f2bf(v * 0.125f);
            else
              Kb[(bh * 2048 + (li0 + r)) * 64 + d] = f2bf(v);
          }
        }
      }
    }
  }
}

// ---------------- flash attention (causal) ----------------
// grid (L/128, B*H); 4 independent waves, each 32 q-rows; KVBLK=32.
__global__ __launch_bounds__(256) void attn_fwd(const unsigned short* __restrict__ Qb,
                                                const unsigned short* __restrict__ Kb,
                                                const unsigned short* __restrict__ VTb,
                                                unsigned short* __restrict__ AO) {
  __shared__ unsigned short plds[4][1280];  // per-wave P tile [32][40] bf16 (pad->2-way only)
  const int bh = blockIdx.y;
  const int q0 = blockIdx.x * 128;
  const int tid = threadIdx.x;
  const int lane = tid & 63, wid = tid >> 6;
  const int l15 = lane & 15, g = lane >> 4, g4 = g * 4;
  const int qlo = q0 + wid * 32;
  const unsigned short* Qp = Qb + (size_t)bh * 2048 * 64;
  const unsigned short* Kp = Kb + (size_t)bh * 2048 * 64;
  const unsigned short* Vp = VTb + (size_t)bh * 64 * 2048;  // [64][2048]
  unsigned short* pl = plds[wid];

  bf16x8 qf[2][2];  // [m][dchunk]  (Q pre-scaled by 0.125)
#pragma unroll
  for (int m = 0; m < 2; ++m)
#pragma unroll
    for (int dc = 0; dc < 2; ++dc)
      qf[m][dc] = *(const bf16x8*)&Qp[(size_t)(qlo + m * 16 + l15) * 64 + dc * 32 + g * 8];

  f32x4 O[2][4];
  float Mx[2][4], Ls[2][4];
#pragma unroll
  for (int m = 0; m < 2; ++m) {
#pragma unroll
    for (int dc = 0; dc < 4; ++dc) O[m][dc] = (f32x4){0.f, 0.f, 0.f, 0.f};
#pragma unroll
    for (int r = 0; r < 4; ++r) { Mx[m][r] = -3e38f; Ls[m][r] = 0.f; }
  }

  const int nkb = (qlo >> 5) + 1;  // causal: only KV blocks touching <= q rows
  for (int ib = 0; ib < nkb; ++ib) {
    const int kb = ib << 5;
    bf16x8 kf[2][2];
#pragma unroll
    for (int kc = 0; kc < 2; ++kc)
#pragma unroll
      for (int dc = 0; dc < 2; ++dc)
        kf[kc][dc] = *(const bf16x8*)&Kp[(size_t)(kb + kc * 16 + l15) * 64 + dc * 32 + g * 8];

    f32x4 S[2][2];
#pragma unroll
    for (int m = 0; m < 2; ++m)
#pragma unroll
      for (int kc = 0; kc < 2; ++kc) {
        f32x4 z = (f32x4){0.f, 0.f, 0.f, 0.f};
        z = __builtin_amdgcn_mfma_f32_16x16x32_bf16(qf[m][0], kf[kc][0], z, 0, 0, 0);
        S[m][kc] = __builtin_amdgcn_mfma_f32_16x16x32_bf16(qf[m][1], kf[kc][1], z, 0, 0, 0);
      }
    // causal mask
#pragma unroll
    for (int m = 0; m < 2; ++m)
#pragma unroll
      for (int kc = 0; kc < 2; ++kc) {
        const int key = kb + kc * 16 + l15;
#pragma unroll
        for (int r = 0; r < 4; ++r) {
          const int q = qlo + m * 16 + g4 + r;
          if (key > q) S[m][kc][r] = -1e30f;
        }
      }
    // online softmax (wave-parallel, width-16 groups)
#pragma unroll
    for (int m = 0; m < 2; ++m) {
#pragma unroll
      for (int r = 0; r < 4; ++r) {
        float mx = fmaxf(S[m][0][r], S[m][1][r]);
        mx = fmaxf(mx, __shfl_xor(mx, 1, 16));
        mx = fmaxf(mx, __shfl_xor(mx, 2, 16));
        mx = fmaxf(mx, __shfl_xor(mx, 4, 16));
        mx = fmaxf(mx, __shfl_xor(mx, 8, 16));
        const float nm = fmaxf(Mx[m][r], mx);
        const float al = __expf(Mx[m][r] - nm);
        Mx[m][r] = nm;
        const float e0 = __expf(S[m][0][r] - nm);
        const float e1 = __expf(S[m][1][r] - nm);
        S[m][0][r] = e0; S[m][1][r] = e1;
        float sm = e0 + e1;
        sm += __shfl_xor(sm, 1, 16);
        sm += __shfl_xor(sm, 2, 16);
        sm += __shfl_xor(sm, 4, 16);
        sm += __shfl_xor(sm, 8, 16);
        Ls[m][r] = Ls[m][r] * al + sm;
#pragma unroll
        for (int dc = 0; dc < 4; ++dc) O[m][dc][r] *= al;
      }
    }
    // P -> LDS (C layout) then read back as A-frag layout (per-wave, no barrier)
#pragma unroll
    for (int m = 0; m < 2; ++m)
#pragma unroll
      for (int kc = 0; kc < 2; ++kc)
#pragma unroll
        for (int r = 0; r < 4; ++r)
          pl[(m * 16 + g4 + r) * 40 + kc * 16 + l15] = f2bf(S[m][kc][r]);
    bf16x8 pa[2];
#pragma unroll
    for (int m = 0; m < 2; ++m)
      pa[m] = *(const bf16x8*)&pl[(m * 16 + l15) * 40 + g * 8];
    bf16x8 vf[4];
#pragma unroll
    for (int dc = 0; dc < 4; ++dc)
      vf[dc] = *(const bf16x8*)&Vp[(size_t)(dc * 16 + l15) * 2048 + kb + g * 8];
#pragma unroll
    for (int m = 0; m < 2; ++m)
#pragma unroll
      for (int dc = 0; dc < 4; ++dc)
        O[m][dc] = __builtin_amdgcn_mfma_f32_16x16x32_bf16(pa[m], vf[dc], O[m][dc], 0, 0, 0);
  }

  const int b = bh >> 4, h = bh & 15;
#pragma unroll
  for (int m = 0; m < 2; ++m)
#pragma unroll
    for (int r = 0; r < 4; ++r) {
      const float inv = 1.0f / Ls[m][r];
      const int row = b * 2048 + qlo + m * 16 + g4 + r;
#pragma unroll
      for (int dc = 0; dc < 4; ++dc) {
        const int col = h * 64 + dc * 16 + l15;
        AO[(size_t)row * 1024 + col] = f2bf(O[m][dc][r] * inv);
      }
    }
}

extern "C" void kernel_launch(void* const* d_in, const int* in_sizes, int n_in,
                              void* d_out, int out_size, void* d_ws, size_t ws_size,
                              hipStream_t stream) {
  const float* x     = (const float*)d_in[0];  // [4,2048,1024]
  const float* w_qkv = (const float*)d_in[1];  // [1024,3072]
  const float* w_out = (const float*)d_in[2];  // [1024,1024]
  float* out = (float*)d_out;                  // [8192,1024]

  // workspace layout (bf16 elems); total 92,372,992 bytes
  unsigned short* xb    = (unsigned short*)d_ws;   // [8192][1024]
  unsigned short* wqkvT = xb + 8388608;            // [3072][1024]
  unsigned short* woutT = wqkvT + 3145728;         // [1024][1024]
  unsigned short* Qb    = woutT + 1048576;         // [B,H,2048,64]
  unsigned short* Kb    = Qb + 8388608;
  unsigned short* VTb   = Kb + 8388608;            // [B,H,64,2048]
  unsigned short* AO    = VTb + 8388608;           // [8192][1024]

  cvt_bf16<<<2048, 256, 0, stream>>>(x, xb, 8388608 / 4);
  transpose_cvt<<<dim3(48, 16), 256, 0, stream>>>(w_qkv, wqkvT, 1024, 3072);
  transpose_cvt<<<dim3(16, 16), 256, 0, stream>>>(w_out, woutT, 1024, 1024);
  gemm_bt<0><<<dim3(24, 64), 256, 0, stream>>>(xb, wqkvT, nullptr, Qb, Kb, VTb,
                                               8192, 3072, 1024);
  attn_fwd<<<dim3(16, 64), 256, 0, stream>>>(Qb, Kb, VTb, AO);
  gemm_bt<1><<<dim3(8, 64), 256, 0, stream>>>(AO, woutT, out, nullptr, nullptr,
                                              nullptr, 8192, 1024, 1024);
}

// Round 2
// 414.653 us; speedup vs baseline: 1.1969x; 1.1969x over previous
//
#include <hip/hip_runtime.h>
#include <hip/hip_bf16.h>

// SimpleAttention: B=4, L=2048, D=1024, H=16, dh=64.
// Pipeline: cvt(x)->bf16 ; transpose-cvt(w_qkv,w_out)->[N][K] bf16 ;
//           QKV GEMM (writes Q*0.125,K as [B,H,L,64], V^T as [B,H,64,L]) ;
//           flash attention (causal, swapped-operand online softmax) -> AO ;
//           out GEMM -> f32 d_out.

typedef __attribute__((ext_vector_type(4))) float f32x4;
typedef __attribute__((ext_vector_type(8))) short bf16x8;

__device__ inline unsigned short f2bf(float f) {
  unsigned int u = __float_as_uint(f);
  u += 0x7FFFu + ((u >> 16) & 1u);   // RNE
  return (unsigned short)(u >> 16);
}

__device__ inline void gl_lds16(const void* g, void* l) {
  __builtin_amdgcn_global_load_lds(
      (const __attribute__((address_space(1))) unsigned int*)g,
      (__attribute__((address_space(3))) unsigned int*)l, 16, 0, 0);
}

// ---------------- elementwise f32 -> bf16 ----------------
__global__ __launch_bounds__(256) void cvt_bf16(const float* __restrict__ src,
                                                unsigned short* __restrict__ dst,
                                                int n4) {
  int stride = gridDim.x * blockDim.x;
  for (int i = blockIdx.x * blockDim.x + threadIdx.x; i < n4; i += stride) {
    float4 v = ((const float4*)src)[i];
    ushort4 o;
    o.x = f2bf(v.x); o.y = f2bf(v.y); o.z = f2bf(v.z); o.w = f2bf(v.w);
    ((ushort4*)dst)[i] = o;
  }
}

// ---------------- transpose + convert: src f32 [K][N] -> dst bf16 [N][K] ----
__global__ __launch_bounds__(256) void transpose_cvt(const float* __restrict__ src,
                                                     unsigned short* __restrict__ dst,
                                                     int K, int N) {
  __shared__ float tile[64][65];
  const int k0 = blockIdx.y * 64, n0 = blockIdx.x * 64;
  const int t = threadIdx.x;
  const int tr = t >> 2, tq = t & 3;
  const float* s = src + (size_t)(k0 + tr) * N + n0 + tq * 16;
#pragma unroll
  for (int i = 0; i < 4; ++i) {
    float4 v = *(const float4*)(s + i * 4);
    tile[tr][tq * 16 + i * 4 + 0] = v.x;
    tile[tr][tq * 16 + i * 4 + 1] = v.y;
    tile[tr][tq * 16 + i * 4 + 2] = v.z;
    tile[tr][tq * 16 + i * 4 + 3] = v.w;
  }
  __syncthreads();
  unsigned short* d = dst + (size_t)(n0 + tr) * K + k0 + tq * 16;
#pragma unroll
  for (int i = 0; i < 4; ++i) {
    ushort4 o;
    o.x = f2bf(tile[tq * 16 + i * 4 + 0][tr]);
    o.y = f2bf(tile[tq * 16 + i * 4 + 1][tr]);
    o.z = f2bf(tile[tq * 16 + i * 4 + 2][tr]);
    o.w = f2bf(tile[tq * 16 + i * 4 + 3][tr]);
    *(ushort4*)(d + i * 4) = o;
  }
}

// ---------------- GEMM: A [M][K] bf16  x  Bt [N][K] bf16 -------------------
// 128x128 tile, BK=64, 4 waves (each 64x64 = 4x4 16x16 frags).
// LDS linear dest + inverse-swizzled global source + swizzled ds_read (rule #21).
template <int EPI>
__global__ __launch_bounds__(256) void gemm_bt(
    const unsigned short* __restrict__ A, const unsigned short* __restrict__ Bt,
    float* __restrict__ Cf,
    unsigned short* __restrict__ Qb, unsigned short* __restrict__ Kb,
    unsigned short* __restrict__ VTb, int M, int N, int K) {
  __shared__ unsigned short lds[16384];
  const int tid = threadIdx.x;
  const int lane = tid & 63, wid = tid >> 6;
  const int wr = wid >> 1, wc = wid & 1;
  const int l15 = lane & 15, g = lane >> 4;
  const int bm = blockIdx.y * 128, bn = blockIdx.x * 128;

  f32x4 acc[4][4];
#pragma unroll
  for (int m = 0; m < 4; ++m)
#pragma unroll
    for (int n = 0; n < 4; ++n) acc[m][n] = (f32x4){0.f, 0.f, 0.f, 0.f};

  const int nkt = K >> 6;
  for (int kt = 0; kt < nkt; ++kt) {
    const int k0 = kt << 6;
#pragma unroll
    for (int i = 0; i < 4; ++i) {
      int seg = wid * 256 + i * 64 + lane;
      int row = seg >> 3, slot = seg & 7;
      int ls = slot ^ (row & 7);
      gl_lds16(A + (size_t)(bm + row) * K + k0 + ls * 8,
               (void*)((char*)lds + seg * 16));
    }
#pragma unroll
    for (int i = 0; i < 4; ++i) {
      int seg = wid * 256 + i * 64 + lane;
      int row = seg >> 3, slot = seg & 7;
      int ls = slot ^ (row & 7);
      gl_lds16(Bt + (size_t)(bn + row) * K + k0 + ls * 8,
               (void*)((char*)lds + 16384 + seg * 16));
    }
    __syncthreads();
#pragma unroll
    for (int ks = 0; ks < 2; ++ks) {
      bf16x8 af[4], bfr[4];
#pragma unroll
      for (int m = 0; m < 4; ++m) {
        int r = wr * 64 + m * 16 + l15;
        int cb = (ks * 64 + g * 16) ^ ((r & 7) << 4);
        af[m] = *(const bf16x8*)((const char*)lds + r * 128 + cb);
      }
#pragma unroll
      for (int n = 0; n < 4; ++n) {
        int r = wc * 64 + n * 16 + l15;
        int cb = (ks * 64 + g * 16) ^ ((r & 7) << 4);
        bfr[n] = *(const bf16x8*)((const char*)lds + 16384 + r * 128 + cb);
      }
#pragma unroll
      for (int m = 0; m < 4; ++m)
#pragma unroll
        for (int n = 0; n < 4; ++n)
          acc[m][n] = __builtin_amdgcn_mfma_f32_16x16x32_bf16(af[m], bfr[n],
                                                              acc[m][n], 0, 0, 0);
    }
    __syncthreads();
  }

  const int g4 = g * 4;
#pragma unroll
  for (int m = 0; m < 4; ++m) {
#pragma unroll
    for (int n = 0; n < 4; ++n) {
      const int col = bn + wc * 64 + n * 16 + l15;
      const int row0 = bm + wr * 64 + m * 16 + g4;
      if (EPI == 1) {
#pragma unroll
        for (int r = 0; r < 4; ++r)
          Cf[(size_t)(row0 + r) * N + col] = acc[m][n][r];
      } else {
        const int t3 = col >> 10, rem = col & 1023;
        const int h = rem >> 6, d = rem & 63;
        const int b = row0 >> 11, li0 = row0 & 2047;
        const size_t bh = (size_t)(b * 16 + h);
        if (t3 == 2) {
          ushort4 o;
          o.x = f2bf(acc[m][n][0]); o.y = f2bf(acc[m][n][1]);
          o.z = f2bf(acc[m][n][2]); o.w = f2bf(acc[m][n][3]);
          *(ushort4*)&VTb[(bh * 64 + d) * 2048 + li0] = o;
        } else {
#pragma unroll
          for (int r = 0; r < 4; ++r) {
            float v = acc[m][n][r];
            if (t3 == 0)
              Qb[(bh * 2048 + (li0 + r)) * 64 + d] = f2bf(v * 0.125f);
            else
              Kb[(bh * 2048 + (li0 + r)) * 64 + d] = f2bf(v);
          }
        }
      }
    }
  }
}

// ---------------- flash attention (causal, swapped-operand) ----------------
// grid (L/128, B*H); 4 independent waves, 32 q-rows each; KVBLK=64.
// S^T = mfma(K,Q): lane holds q = l15 column -> in-lane softmax reduce.
// O^T = mfma(V^T, P): q stays lane-local for rescale and 1/L.
__global__ __launch_bounds__(256) void attn_fwd(const unsigned short* __restrict__ Qb,
                                                const unsigned short* __restrict__ Kb,
                                                const unsigned short* __restrict__ VTb,
                                                unsigned short* __restrict__ AO) {
  __shared__ unsigned short plds[4][2048];  // per-wave P tile [32 q][64 key], XOR-swizzled
  const int bh = blockIdx.y;
  const int tid = threadIdx.x;
  const int lane = tid & 63, wid = tid >> 6;
  const int l15 = lane & 15, g = lane >> 4, g4 = g * 4;
  const int qlo = blockIdx.x * 128 + wid * 32;
  const unsigned short* Qp = Qb + (size_t)bh * 2048 * 64;
  const unsigned short* Kp = Kb + (size_t)bh * 2048 * 64;
  const unsigned short* Vp = VTb + (size_t)bh * 64 * 2048;  // [64][2048]
  char* pl = (char*)plds[wid];
  const int swz = (l15 & 7) << 4;

  bf16x8 qf[2][2];  // [m][dchunk]  (Q pre-scaled by 0.125)
#pragma unroll
  for (int m = 0; m < 2; ++m)
#pragma unroll
    for (int dc = 0; dc < 2; ++dc)
      qf[m][dc] = *(const bf16x8*)&Qp[(size_t)(qlo + m * 16 + l15) * 64 + dc * 32 + g * 8];

  f32x4 Ot[4][2];  // [dc: d 16-block][m: q 16-block]; row g4+r = d, col l15 = q
  float Mx[2] = {-3e38f, -3e38f}, Ls[2] = {0.f, 0.f};
#pragma unroll
  for (int dc = 0; dc < 4; ++dc)
#pragma unroll
    for (int m = 0; m < 2; ++m) Ot[dc][m] = (f32x4){0.f, 0.f, 0.f, 0.f};

  const int nkb = (qlo >> 6) + 1;  // KV-64 blocks; kb <= qlo so no row fully masked
  const int c0 = g4 - l15 - qlo;   // (key - q) = c0 + kb + kc*16 + r - m*16

  auto body = [&](int kb, bool domask) {
    bf16x8 kf[4][2];
#pragma unroll
    for (int kc = 0; kc < 4; ++kc)
#pragma unroll
      for (int dc = 0; dc < 2; ++dc)
        kf[kc][dc] = *(const bf16x8*)&Kp[(size_t)(kb + kc * 16 + l15) * 64 + dc * 32 + g * 8];

    f32x4 St[4][2];  // S^T frag: row g4+r = key within kc block, col l15 = q within m block
#pragma unroll
    for (int kc = 0; kc < 4; ++kc)
#pragma unroll
      for (int m = 0; m < 2; ++m) {
        f32x4 z = (f32x4){0.f, 0.f, 0.f, 0.f};
        z = __builtin_amdgcn_mfma_f32_16x16x32_bf16(kf[kc][0], qf[m][0], z, 0, 0, 0);
        St[kc][m] = __builtin_amdgcn_mfma_f32_16x16x32_bf16(kf[kc][1], qf[m][1], z, 0, 0, 0);
      }
    if (domask) {
      const int base = c0 + kb;
#pragma unroll
      for (int kc = 0; kc < 4; ++kc)
#pragma unroll
        for (int m = 0; m < 2; ++m)
#pragma unroll
          for (int r = 0; r < 4; ++r)
            if (base + kc * 16 + r > m * 16) St[kc][m][r] = -1e30f;
    }
#pragma unroll
    for (int m = 0; m < 2; ++m) {
      // in-lane max over 16 (kc x r), then reduce across the 4 g-groups
      float t0 = fmaxf(fmaxf(St[0][m][0], St[0][m][1]), fmaxf(St[0][m][2], St[0][m][3]));
      float t1 = fmaxf(fmaxf(St[1][m][0], St[1][m][1]), fmaxf(St[1][m][2], St[1][m][3]));
      float t2 = fmaxf(fmaxf(St[2][m][0], St[2][m][1]), fmaxf(St[2][m][2], St[2][m][3]));
      float t3 = fmaxf(fmaxf(St[3][m][0], St[3][m][1]), fmaxf(St[3][m][2], St[3][m][3]));
      float tm = fmaxf(fmaxf(t0, t1), fmaxf(t2, t3));
      tm = fmaxf(tm, __shfl_xor(tm, 16));
      tm = fmaxf(tm, __shfl_xor(tm, 32));
      if (!__all(tm <= Mx[m] + 8.f)) {  // defer-max (T13)
        const float nm = fmaxf(Mx[m], tm);
        const float al = __expf(Mx[m] - nm);
        Mx[m] = nm;
        Ls[m] *= al;
#pragma unroll
        for (int dc = 0; dc < 4; ++dc)
#pragma unroll
          for (int r = 0; r < 4; ++r) Ot[dc][m][r] *= al;
      }
      float sm = 0.f;
#pragma unroll
      for (int kc = 0; kc < 4; ++kc) {
        ushort4 o;
#pragma unroll
        for (int r = 0; r < 4; ++r) {
          float e = __expf(St[kc][m][r] - Mx[m]);
          sm += e;
          ((unsigned short*)&o)[r] = f2bf(e);
        }
        *(ushort4*)(pl + (m * 16 + l15) * 128 + ((kc * 32 + g * 8) ^ swz)) = o;
      }
      sm += __shfl_xor(sm, 16);
      sm += __shfl_xor(sm, 32);
      Ls[m] += sm;
    }
    // P back as B-fragments (same wave; compiler inserts lgkmcnt)
    bf16x8 pa[2][2];
#pragma unroll
    for (int m = 0; m < 2; ++m)
#pragma unroll
      for (int c = 0; c < 2; ++c)
        pa[m][c] = *(const bf16x8*)(pl + (m * 16 + l15) * 128 + ((c * 64 + g * 16) ^ swz));
#pragma unroll
    for (int c = 0; c < 2; ++c) {
      bf16x8 vf[4];
#pragma unroll
      for (int dc = 0; dc < 4; ++dc)
        vf[dc] = *(const bf16x8*)&Vp[(size_t)(dc * 16 + l15) * 2048 + kb + c * 32 + g * 8];
#pragma unroll
      for (int dc = 0; dc < 4; ++dc)
#pragma unroll
        for (int m = 0; m < 2; ++m)
          Ot[dc][m] = __builtin_amdgcn_mfma_f32_16x16x32_bf16(vf[dc], pa[m][c],
                                                              Ot[dc][m], 0, 0, 0);
    }
  };

  for (int ib = 0; ib < nkb - 1; ++ib) body(ib << 6, false);
  body((nkb - 1) << 6, true);

  const int b = bh >> 4, h = bh & 15;
#pragma unroll
  for (int m = 0; m < 2; ++m) {
    const float inv = 1.0f / Ls[m];
    const size_t row = (size_t)(b * 2048 + qlo + m * 16 + l15) * 1024 + h * 64;
#pragma unroll
    for (int dc = 0; dc < 4; ++dc) {
      ushort4 o;
#pragma unroll
      for (int r = 0; r < 4; ++r) ((unsigned short*)&o)[r] = f2bf(Ot[dc][m][r] * inv);
      *(ushort4*)&AO[row + dc * 16 + g4] = o;
    }
  }
}

extern "C" void kernel_launch(void* const* d_in, const int* in_sizes, int n_in,
                              void* d_out, int out_size, void* d_ws, size_t ws_size,
                              hipStream_t stream) {
  const float* x     = (const float*)d_in[0];  // [4,2048,1024]
  const float* w_qkv = (const float*)d_in[1];  // [1024,3072]
  const float* w_out = (const float*)d_in[2];  // [1024,1024]
  float* out = (float*)d_out;                  // [8192,1024]

  unsigned short* xb    = (unsigned short*)d_ws;   // [8192][1024]
  unsigned short* wqkvT = xb + 8388608;            // [3072][1024]
  unsigned short* woutT = wqkvT + 3145728;         // [1024][1024]
  unsigned short* Qb    = woutT + 1048576;         // [B,H,2048,64]
  unsigned short* Kb    = Qb + 8388608;
  unsigned short* VTb   = Kb + 8388608;            // [B,H,64,2048]
  unsigned short* AO    = VTb + 8388608;           // [8192][1024]

  cvt_bf16<<<2048, 256, 0, stream>>>(x, xb, 8388608 / 4);
  transpose_cvt<<<dim3(48, 16), 256, 0, stream>>>(w_qkv, wqkvT, 1024, 3072);
  transpose_cvt<<<dim3(16, 16), 256, 0, stream>>>(w_out, woutT, 1024, 1024);
  gemm_bt<0><<<dim3(24, 64), 256, 0, stream>>>(xb, wqkvT, nullptr, Qb, Kb, VTb,
                                               8192, 3072, 1024);
  attn_fwd<<<dim3(16, 64), 256, 0, stream>>>(Qb, Kb, VTb, AO);
  gemm_bt<1><<<dim3(8, 64), 256, 0, stream>>>(AO, woutT, out, nullptr, nullptr,
                                              nullptr, 8192, 1024, 1024);
}

// Round 8
// 266.183 us; speedup vs baseline: 1.8645x; 1.5578x over previous
//
#include <hip/hip_runtime.h>
#include <hip/hip_bf16.h>

// SimpleAttention: B=4, L=2048, D=1024, H=16, dh=64.
// cvt(x)->bf16 ; transpose-cvt(w_qkv,w_out) ; QKV GEMM -> Q*0.125,K,[B,H,64,L] V^T ;
// flash attention (causal, swapped-operand, balanced pairing, LDS-staged KV) ;
// out GEMM -> f32.

typedef __attribute__((ext_vector_type(4))) float f32x4;
typedef __attribute__((ext_vector_type(8))) short bf16x8;

__device__ inline unsigned short f2bf(float f) {
  unsigned int u = __float_as_uint(f);
  u += 0x7FFFu + ((u >> 16) & 1u);   // RNE
  return (unsigned short)(u >> 16);
}

__device__ inline void gl_lds16(const void* g, void* l) {
  __builtin_amdgcn_global_load_lds(
      (const __attribute__((address_space(1))) unsigned int*)g,
      (__attribute__((address_space(3))) unsigned int*)l, 16, 0, 0);
}

// ---------------- elementwise f32 -> bf16 ----------------
__global__ __launch_bounds__(256) void cvt_bf16(const float* __restrict__ src,
                                                unsigned short* __restrict__ dst,
                                                int n4) {
  int stride = gridDim.x * blockDim.x;
  for (int i = blockIdx.x * blockDim.x + threadIdx.x; i < n4; i += stride) {
    float4 v = ((const float4*)src)[i];
    ushort4 o;
    o.x = f2bf(v.x); o.y = f2bf(v.y); o.z = f2bf(v.z); o.w = f2bf(v.w);
    ((ushort4*)dst)[i] = o;
  }
}

// ---------------- transpose + convert: src f32 [K][N] -> dst bf16 [N][K] ----
__global__ __launch_bounds__(256) void transpose_cvt(const float* __restrict__ src,
                                                     unsigned short* __restrict__ dst,
                                                     int K, int N) {
  __shared__ float tile[64][65];
  const int k0 = blockIdx.y * 64, n0 = blockIdx.x * 64;
  const int t = threadIdx.x;
  const int tr = t >> 2, tq = t & 3;
  const float* s = src + (size_t)(k0 + tr) * N + n0 + tq * 16;
#pragma unroll
  for (int i = 0; i < 4; ++i) {
    float4 v = *(const float4*)(s + i * 4);
    tile[tr][tq * 16 + i * 4 + 0] = v.x;
    tile[tr][tq * 16 + i * 4 + 1] = v.y;
    tile[tr][tq * 16 + i * 4 + 2] = v.z;
    tile[tr][tq * 16 + i * 4 + 3] = v.w;
  }
  __syncthreads();
  unsigned short* d = dst + (size_t)(n0 + tr) * K + k0 + tq * 16;
#pragma unroll
  for (int i = 0; i < 4; ++i) {
    ushort4 o;
    o.x = f2bf(tile[tq * 16 + i * 4 + 0][tr]);
    o.y = f2bf(tile[tq * 16 + i * 4 + 1][tr]);
    o.z = f2bf(tile[tq * 16 + i * 4 + 2][tr]);
    o.w = f2bf(tile[tq * 16 + i * 4 + 3][tr]);
    *(ushort4*)(d + i * 4) = o;
  }
}

// ---------------- GEMM: A [M][K] bf16  x  Bt [N][K] bf16 -------------------
template <int EPI>
__global__ __launch_bounds__(256) void gemm_bt(
    const unsigned short* __restrict__ A, const unsigned short* __restrict__ Bt,
    float* __restrict__ Cf,
    unsigned short* __restrict__ Qb, unsigned short* __restrict__ Kb,
    unsigned short* __restrict__ VTb, int M, int N, int K) {
  __shared__ unsigned short lds[16384];
  const int tid = threadIdx.x;
  const int lane = tid & 63, wid = tid >> 6;
  const int wr = wid >> 1, wc = wid & 1;
  const int l15 = lane & 15, g = lane >> 4;
  const int bm = blockIdx.y * 128, bn = blockIdx.x * 128;

  f32x4 acc[4][4];
#pragma unroll
  for (int m = 0; m < 4; ++m)
#pragma unroll
    for (int n = 0; n < 4; ++n) acc[m][n] = (f32x4){0.f, 0.f, 0.f, 0.f};

  const int nkt = K >> 6;
  for (int kt = 0; kt < nkt; ++kt) {
    const int k0 = kt << 6;
#pragma unroll
    for (int i = 0; i < 4; ++i) {
      int seg = wid * 256 + i * 64 + lane;
      int row = seg >> 3, slot = seg & 7;
      int ls = slot ^ (row & 7);
      gl_lds16(A + (size_t)(bm + row) * K + k0 + ls * 8,
               (void*)((char*)lds + seg * 16));
    }
#pragma unroll
    for (int i = 0; i < 4; ++i) {
      int seg = wid * 256 + i * 64 + lane;
      int row = seg >> 3, slot = seg & 7;
      int ls = slot ^ (row & 7);
      gl_lds16(Bt + (size_t)(bn + row) * K + k0 + ls * 8,
               (void*)((char*)lds + 16384 + seg * 16));
    }
    __syncthreads();
#pragma unroll
    for (int ks = 0; ks < 2; ++ks) {
      bf16x8 af[4], bfr[4];
#pragma unroll
      for (int m = 0; m < 4; ++m) {
        int r = wr * 64 + m * 16 + l15;
        int cb = (ks * 64 + g * 16) ^ ((r & 7) << 4);
        af[m] = *(const bf16x8*)((const char*)lds + r * 128 + cb);
      }
#pragma unroll
      for (int n = 0; n < 4; ++n) {
        int r = wc * 64 + n * 16 + l15;
        int cb = (ks * 64 + g * 16) ^ ((r & 7) << 4);
        bfr[n] = *(const bf16x8*)((const char*)lds + 16384 + r * 128 + cb);
      }
#pragma unroll
      for (int m = 0; m < 4; ++m)
#pragma unroll
        for (int n = 0; n < 4; ++n)
          acc[m][n] = __builtin_amdgcn_mfma_f32_16x16x32_bf16(af[m], bfr[n],
                                                              acc[m][n], 0, 0, 0);
    }
    __syncthreads();
  }

  const int g4 = g * 4;
#pragma unroll
  for (int m = 0; m < 4; ++m) {
#pragma unroll
    for (int n = 0; n < 4; ++n) {
      const int col = bn + wc * 64 + n * 16 + l15;
      const int row0 = bm + wr * 64 + m * 16 + g4;
      if (EPI == 1) {
#pragma unroll
        for (int r = 0; r < 4; ++r)
          Cf[(size_t)(row0 + r) * N + col] = acc[m][n][r];
      } else {
        const int t3 = col >> 10, rem = col & 1023;
        const int h = rem >> 6, d = rem & 63;
        const int b = row0 >> 11, li0 = row0 & 2047;
        const size_t bh = (size_t)(b * 16 + h);
        if (t3 == 2) {
          ushort4 o;
          o.x = f2bf(acc[m][n][0]); o.y = f2bf(acc[m][n][1]);
          o.z = f2bf(acc[m][n][2]); o.w = f2bf(acc[m][n][3]);
          *(ushort4*)&VTb[(bh * 64 + d) * 2048 + li0] = o;
        } else {
#pragma unroll
          for (int r = 0; r < 4; ++r) {
            float v = acc[m][n][r];
            if (t3 == 0)
              Qb[(bh * 2048 + (li0 + r)) * 64 + d] = f2bf(v * 0.125f);
            else
              Kb[(bh * 2048 + (li0 + r)) * 64 + d] = f2bf(v);
          }
        }
      }
    }
  }
}

// ---------------- flash attention (causal, swapped-operand, paired tiles) ---
// grid (16, B*H), 128 threads (2 waves x 32 q-rows => 64-row q-tile).
// Block x does q-tile (31-x) then q-tile x  => exactly 33 KV-iterations/block.
// K,V 64x64 tiles double-buffered in LDS (global_load_lds + XOR swizzle).
__global__ __launch_bounds__(128) void attn_fwd(const unsigned short* __restrict__ Qb,
                                                const unsigned short* __restrict__ Kb,
                                                const unsigned short* __restrict__ VTb,
                                                unsigned short* __restrict__ AO) {
  __shared__ unsigned short kvlds[2][8192];  // [buf][ K 64x64 | V 64x64 ] shorts
  __shared__ unsigned short plds[2][2048];   // per-wave P tile [32 q][64 key]
  const int bh = blockIdx.y;
  const int tid = threadIdx.x;
  const int lane = tid & 63, wid = tid >> 6;
  const int l15 = lane & 15, g = lane >> 4, g4 = g * 4;
  const unsigned short* Qp = Qb + (size_t)bh * 2048 * 64;
  const unsigned short* Kp = Kb + (size_t)bh * 2048 * 64;
  const unsigned short* Vp = VTb + (size_t)bh * 64 * 2048;  // [64][2048]
  char* pl = (char*)plds[wid];
  const int swz = (l15 & 7) << 4;
  const int b = bh >> 4, h = bh & 15;

  auto stage = [&](int kb, int buf) {
    unsigned short* base = kvlds[buf];
    const unsigned short* Ks = Kp + kb * 64 * 64;
    const unsigned short* Vs = Vp + kb * 64;
#pragma unroll
    for (int i = 0; i < 4; ++i) {  // K: 512 segs of 16B over 128 threads
      int seg = wid * 256 + i * 64 + lane;
      int row = seg >> 3, sl = (seg & 7) ^ (row & 7);
      gl_lds16(Ks + row * 64 + sl * 8, (char*)base + seg * 16);
    }
#pragma unroll
    for (int i = 0; i < 4; ++i) {  // V
      int seg = wid * 256 + i * 64 + lane;
      int row = seg >> 3, sl = (seg & 7) ^ (row & 7);
      gl_lds16(Vs + (size_t)row * 2048 + sl * 8, (char*)(base + 4096) + seg * 16);
    }
  };

#pragma unroll 1
  for (int ph = 0; ph < 2; ++ph) {
    const int qt = ph ? blockIdx.x : 31 - blockIdx.x;
    const int qlo = qt * 64 + wid * 32;
    const int nkb = qt + 1;  // KV-64 blocks 0..qt
    const int c0 = g4 - l15 - qlo;

    bf16x8 qf[2][2];
#pragma unroll
    for (int m = 0; m < 2; ++m)
#pragma unroll
      for (int dc = 0; dc < 2; ++dc)
        qf[m][dc] = *(const bf16x8*)&Qp[(size_t)(qlo + m * 16 + l15) * 64 + dc * 32 + g * 8];

    f32x4 Ot[4][2];  // [d-block][q-block]; row g4+r = d, col l15 = q
    float Mx[2] = {-3e38f, -3e38f}, Ls[2] = {0.f, 0.f};
#pragma unroll
    for (int dc = 0; dc < 4; ++dc)
#pragma unroll
      for (int m = 0; m < 2; ++m) Ot[dc][m] = (f32x4){0.f, 0.f, 0.f, 0.f};

    stage(0, 0);
    __syncthreads();

#pragma unroll 1
    for (int kb = 0; kb < nkb; ++kb) {
      const int buf = kb & 1;
      if (kb + 1 < nkb) stage(kb + 1, buf ^ 1);

      const char* kbase = (const char*)kvlds[buf];
      const char* vbase = kbase + 8192;

      bf16x8 kf[4][2];
#pragma unroll
      for (int kc = 0; kc < 4; ++kc) {
        const int row = kc * 16 + l15;
#pragma unroll
        for (int dc = 0; dc < 2; ++dc)
          kf[kc][dc] = *(const bf16x8*)(kbase + row * 128 + ((dc * 64 + g * 16) ^ swz));
      }

      f32x4 St[4][2];
      __builtin_amdgcn_s_setprio(1);
#pragma unroll
      for (int kc = 0; kc < 4; ++kc)
#pragma unroll
        for (int m = 0; m < 2; ++m) {
          f32x4 z = (f32x4){0.f, 0.f, 0.f, 0.f};
          z = __builtin_amdgcn_mfma_f32_16x16x32_bf16(kf[kc][0], qf[m][0], z, 0, 0, 0);
          St[kc][m] = __builtin_amdgcn_mfma_f32_16x16x32_bf16(kf[kc][1], qf[m][1], z, 0, 0, 0);
        }
      __builtin_amdgcn_s_setprio(0);

      if (kb == qt) {  // only the diagonal block needs masking
        const int base = c0 + kb * 64;
#pragma unroll
        for (int kc = 0; kc < 4; ++kc)
#pragma unroll
          for (int m = 0; m < 2; ++m)
#pragma unroll
            for (int r = 0; r < 4; ++r)
              if (base + kc * 16 + r > m * 16) St[kc][m][r] = -1e30f;
      }

#pragma unroll
      for (int m = 0; m < 2; ++m) {
        float t0 = fmaxf(fmaxf(St[0][m][0], St[0][m][1]), fmaxf(St[0][m][2], St[0][m][3]));
        float t1 = fmaxf(fmaxf(St[1][m][0], St[1][m][1]), fmaxf(St[1][m][2], St[1][m][3]));
        float t2 = fmaxf(fmaxf(St[2][m][0], St[2][m][1]), fmaxf(St[2][m][2], St[2][m][3]));
        float t3 = fmaxf(fmaxf(St[3][m][0], St[3][m][1]), fmaxf(St[3][m][2], St[3][m][3]));
        float tm = fmaxf(fmaxf(t0, t1), fmaxf(t2, t3));
        tm = fmaxf(tm, __shfl_xor(tm, 16));
        tm = fmaxf(tm, __shfl_xor(tm, 32));
        if (!__all(tm <= Mx[m] + 8.f)) {  // defer-max (T13)
          const float nm = fmaxf(Mx[m], tm);
          const float al = __expf(Mx[m] - nm);
          Mx[m] = nm;
          Ls[m] *= al;
#pragma unroll
          for (int dc = 0; dc < 4; ++dc)
#pragma unroll
            for (int r = 0; r < 4; ++r) Ot[dc][m][r] *= al;
        }
        float sm = 0.f;
#pragma unroll
        for (int kc = 0; kc < 4; ++kc) {
          ushort4 o;
#pragma unroll
          for (int r = 0; r < 4; ++r) {
            float e = __expf(St[kc][m][r] - Mx[m]);
            sm += e;
            ((unsigned short*)&o)[r] = f2bf(e);
          }
          *(ushort4*)(pl + (m * 16 + l15) * 128 + ((kc * 32 + g * 8) ^ swz)) = o;
        }
        sm += __shfl_xor(sm, 16);
        sm += __shfl_xor(sm, 32);
        Ls[m] += sm;
      }

      bf16x8 pa[2][2];
#pragma unroll
      for (int m = 0; m < 2; ++m)
#pragma unroll
        for (int c = 0; c < 2; ++c)
          pa[m][c] = *(const bf16x8*)(pl + (m * 16 + l15) * 128 + ((c * 64 + g * 16) ^ swz));

#pragma unroll
      for (int c = 0; c < 2; ++c) {
        bf16x8 vf[4];
#pragma unroll
        for (int dc = 0; dc < 4; ++dc) {
          const int row = dc * 16 + l15;
          vf[dc] = *(const bf16x8*)(vbase + row * 128 + ((c * 64 + g * 16) ^ swz));
        }
        __builtin_amdgcn_s_setprio(1);
#pragma unroll
        for (int dc = 0; dc < 4; ++dc)
#pragma unroll
          for (int m = 0; m < 2; ++m)
            Ot[dc][m] = __builtin_amdgcn_mfma_f32_16x16x32_bf16(vf[dc], pa[m][c],
                                                                Ot[dc][m], 0, 0, 0);
        __builtin_amdgcn_s_setprio(0);
      }

      __syncthreads();  // drains vmcnt: tile kb+1 resident; buf safe to reuse
    }

#pragma unroll
    for (int m = 0; m < 2; ++m) {
      const float inv = 1.0f / Ls[m];
      const size_t row = (size_t)(b * 2048 + qlo + m * 16 + l15) * 1024 + h * 64;
#pragma unroll
      for (int dc = 0; dc < 4; ++dc) {
        ushort4 o;
#pragma unroll
        for (int r = 0; r < 4; ++r) ((unsigned short*)&o)[r] = f2bf(Ot[dc][m][r] * inv);
        *(ushort4*)&AO[row + dc * 16 + g4] = o;
      }
    }
    __syncthreads();  // phase results written; safe to restage buf 0
  }
}

extern "C" void kernel_launch(void* const* d_in, const int* in_sizes, int n_in,
                              void* d_out, int out_size, void* d_ws, size_t ws_size,
                              hipStream_t stream) {
  const float* x     = (const float*)d_in[0];  // [4,2048,1024]
  const float* w_qkv = (const float*)d_in[1];  // [1024,3072]
  const float* w_out = (const float*)d_in[2];  // [1024,1024]
  float* out = (float*)d_out;                  // [8192,1024]

  unsigned short* xb    = (unsigned short*)d_ws;   // [8192][1024]
  unsigned short* wqkvT = xb + 8388608;            // [3072][1024]
  unsigned short* woutT = wqkvT + 3145728;         // [1024][1024]
  unsigned short* Qb    = woutT + 1048576;         // [B,H,2048,64]
  unsigned short* Kb    = Qb + 8388608;
  unsigned short* VTb   = Kb + 8388608;            // [B,H,64,2048]
  unsigned short* AO    = VTb + 8388608;           // [8192][1024]

  cvt_bf16<<<2048, 256, 0, stream>>>(x, xb, 8388608 / 4);
  transpose_cvt<<<dim3(48, 16), 256, 0, stream>>>(w_qkv, wqkvT, 1024, 3072);
  transpose_cvt<<<dim3(16, 16), 256, 0, stream>>>(w_out, woutT, 1024, 1024);
  gemm_bt<0><<<dim3(24, 64), 256, 0, stream>>>(xb, wqkvT, nullptr, Qb, Kb, VTb,
                                               8192, 3072, 1024);
  attn_fwd<<<dim3(16, 64), 128, 0, stream>>>(Qb, Kb, VTb, AO);
  gemm_bt<1><<<dim3(8, 64), 256, 0, stream>>>(AO, woutT, out, nullptr, nullptr,
                                              nullptr, 8192, 1024, 1024);
}